// Round 9
// baseline (336.722 us; speedup 1.0000x reference)
//
#include <hip/hip_runtime.h>

// GCN 3-layer: out = GCNconv3(relu(GCNconv2(relu(GCNconv1(x)))))
//
// R9: agg is line-fill-concurrency bound (0.12 lines/cyc/CU ~ MSHR/latency;
// bytes/4 (R5), instrs/2 (R7) both neutral; R8's split regressed because its
// own CSR+out streams re-polluted L2). Fix latency properly:
//   - F=64 agg split by FEATURE into 2 independent dispatches, each gathering
//     one 64B line per row (working set 3.2 MB < 4 MB/XCD L2), each writing
//     its own 32 output columns (no RMW, no cross-pass dependency).
//   - Edge-list loads + out stores NONTEMPORAL: only xw allocates in L2.
//   - 4 edges per vmem (16 lanes/row); dead lanes padded with w=0,s=0
//     (row-0 gathers are L1-hot) -> no tail branches.
//   - F=40 layer: single pass (4.0 MB ws) + NT streams, 2 edges/vmem.
//
// Pipeline:
//   A. bin_scatter: 4096-edge tiles LDS-sorted by bin (bin = dst>>8).
//   B. bin_group (R6): per-bin 256-key counting sort -> CSR + deg/dinv free.
//   C. per layer: fp32 GEMM -> bf16 Y[s] = dinv[s]*(X@W)[s];
//      agg: out = dinv[d]*(sum_e ew*Y[s] + Y[d]) + b.

#define TILE 4096
#define BCAP_MAX 9216   // per-bin capacity; bin load ~Binom mean 8163 sd 90

static __device__ __forceinline__ float4 f4zero() { return make_float4(0.f, 0.f, 0.f, 0.f); }

static __device__ __forceinline__ unsigned short f2bf_rne(float x) {
    unsigned u = __float_as_uint(x);
    u += 0x7FFFu + ((u >> 16) & 1u);     // round-to-nearest-even
    return (unsigned short)(u >> 16);
}
static __device__ __forceinline__ float bflo(unsigned d) { return __uint_as_float(d << 16); }
static __device__ __forceinline__ float bfhi(unsigned d) { return __uint_as_float(d & 0xFFFF0000u); }

// ---------------- Pass A: tile-level LDS binning ----------------
__global__ __launch_bounds__(1024) void bin_scatter_kernel(
        const int* __restrict__ src, const int* __restrict__ dst,
        const float* __restrict__ ew, int* __restrict__ bin_cursor,
        int2* __restrict__ binned, int E, int bcap) {
    __shared__ int cnt[256];
    __shared__ int scan[256];
    __shared__ int gbase[256];
    __shared__ int2 sorted[TILE];
    __shared__ unsigned char binof[TILE];
    const int tid = threadIdx.x;
    const int e0 = blockIdx.x * TILE;

    if (tid < 256) cnt[tid] = 0;
    __syncthreads();

    int mypk[4]; float myew[4]; int mybin[4]; int myrank[4]; bool myok[4];
    #pragma unroll
    for (int j = 0; j < 4; ++j) {
        int e = e0 + j * 1024 + tid;
        myok[j] = (e < E);
        if (myok[j]) {
            int d = dst[e];
            int s = src[e];
            myew[j]   = ew[e];
            mybin[j]  = d >> 8;
            mypk[j]   = (s << 8) | (d & 255);     // src:24b | dst_local:8b
            myrank[j] = atomicAdd(&cnt[mybin[j]], 1);
        }
    }
    __syncthreads();
    if (tid < 256) scan[tid] = cnt[tid];
    __syncthreads();
    for (int off = 1; off < 256; off <<= 1) {     // inclusive Hillis-Steele
        int v = 0;
        if (tid < 256) { v = scan[tid]; if (tid >= off) v += scan[tid - off]; }
        __syncthreads();
        if (tid < 256) scan[tid] = v;
        __syncthreads();
    }
    if (tid < 256 && cnt[tid] > 0)
        gbase[tid] = atomicAdd(&bin_cursor[tid], cnt[tid]);
    __syncthreads();
    #pragma unroll
    for (int j = 0; j < 4; ++j) {
        if (myok[j]) {
            int b = mybin[j];
            int slot = (scan[b] - cnt[b]) + myrank[j];   // excl prefix + rank
            sorted[slot] = make_int2(mypk[j], __float_as_int(myew[j]));
            binof[slot]  = (unsigned char)b;
        }
    }
    __syncthreads();
    const int total = scan[255];
    for (int i = tid; i < total; i += 1024) {
        int b = binof[i];
        int pos = gbase[b] + (i - (scan[b] - cnt[b]));
        if (pos < bcap)   // statistically unreachable; prevents OOB
            binned[(size_t)b * bcap + pos] = sorted[i];
    }
}

// ---------------- Pass B: per-bin counting sort -> CSR (+ deg/dinv) --------
__global__ __launch_bounds__(1024) void bin_group_kernel(
        int2* __restrict__ binned, const int* __restrict__ bin_cursor,
        int* __restrict__ row_start, int* __restrict__ row_cnt,
        float* __restrict__ dinv, int N, int bcap) {
    __shared__ int   cntl[256];
    __shared__ float degl[256];
    __shared__ int   scan[256];
    __shared__ int   run[256];
    __shared__ int2  sorted[BCAP_MAX];
    const int b = blockIdx.x;
    const int tid = threadIdx.x;
    int n = bin_cursor[b];
    if (n > bcap) n = bcap;
    if (tid < 256) { cntl[tid] = 0; degl[tid] = 0.f; }
    __syncthreads();

    int2* seg = binned + (size_t)b * bcap;
    for (int i = tid; i < n; i += 1024) {
        int2 v = seg[i];
        int dl = v.x & 255;
        atomicAdd(&cntl[dl], 1);
        atomicAdd(&degl[dl], __int_as_float(v.y));
    }
    __syncthreads();
    if (tid < 256) scan[tid] = cntl[tid];
    __syncthreads();
    for (int off = 1; off < 256; off <<= 1) {
        int v = 0;
        if (tid < 256) { v = scan[tid]; if (tid >= off) v += scan[tid - off]; }
        __syncthreads();
        if (tid < 256) scan[tid] = v;
        __syncthreads();
    }
    if (tid < 256) {
        int ex = scan[tid] - cntl[tid];
        int d = (b << 8) + tid;
        if (d < N) {
            row_start[d] = b * bcap + ex;
            row_cnt[d]   = cntl[tid];
            dinv[d]      = rsqrtf(degl[tid] + 1.0f);
        }
        run[tid] = ex;
    }
    __syncthreads();
    for (int i = tid; i < n; i += 1024) {
        int2 v = seg[i];
        int dl = v.x & 255;
        int r = atomicAdd(&run[dl], 1);
        sorted[r] = make_int2(v.x >> 8, v.y);    // {src, ew}
    }
    __syncthreads();
    for (int i = tid; i < n; i += 1024)          // in-place: reads done above
        seg[i] = sorted[i];
}

// --- GEMM: Y[N,M](bf16) = dinv[r] * (X[N,K](fp32) @ W[K,M](fp32)), RNE -----
template <int K, int M>
__global__ __launch_bounds__(256) void gemm_kernel(const float* __restrict__ X,
        const float* __restrict__ W, const float* __restrict__ dinv,
        unsigned short* __restrict__ Y, int N) {
    constexpr int KP = K + 4;
    __shared__ float xs[64 * KP];
    __shared__ float ws[K * M];
    const int tid = threadIdx.x;
    const int row0 = blockIdx.x * 64;

    for (int i = tid * 4; i < K * M; i += 1024)
        *(float4*)&ws[i] = *(const float4*)&W[i];

    const int nrows = min(64, N - row0);
    for (int i = tid * 4; i < 64 * K; i += 1024) {
        int r = i / K, k = i % K;
        float4 v = f4zero();
        if (r < nrows) v = *(const float4*)&X[(size_t)(row0 + r) * K + k];
        *(float4*)&xs[r * KP + k] = v;
    }
    __syncthreads();

    const int ct = tid & 15, rt = tid >> 4;
    const bool cok = (ct * 4 < M);
    float acc[4][4] = {};
    for (int k = 0; k < K; ++k) {
        float a0 = xs[(rt +  0) * KP + k];
        float a1 = xs[(rt + 16) * KP + k];
        float a2 = xs[(rt + 32) * KP + k];
        float a3 = xs[(rt + 48) * KP + k];
        float4 bv = cok ? *(const float4*)&ws[k * M + ct * 4] : f4zero();
        acc[0][0] += a0 * bv.x; acc[0][1] += a0 * bv.y; acc[0][2] += a0 * bv.z; acc[0][3] += a0 * bv.w;
        acc[1][0] += a1 * bv.x; acc[1][1] += a1 * bv.y; acc[1][2] += a1 * bv.z; acc[1][3] += a1 * bv.w;
        acc[2][0] += a2 * bv.x; acc[2][1] += a2 * bv.y; acc[2][2] += a2 * bv.z; acc[2][3] += a2 * bv.w;
        acc[3][0] += a3 * bv.x; acc[3][1] += a3 * bv.y; acc[3][2] += a3 * bv.z; acc[3][3] += a3 * bv.w;
    }
    if (cok) {
        #pragma unroll
        for (int i = 0; i < 4; ++i) {
            int r = row0 + rt + 16 * i;
            if (r < N) {
                float dd = dinv[r];
                ushort4 o;
                o.x = f2bf_rne(acc[i][0] * dd); o.y = f2bf_rne(acc[i][1] * dd);
                o.z = f2bf_rne(acc[i][2] * dd); o.w = f2bf_rne(acc[i][3] * dd);
                *(ushort4*)&Y[(size_t)r * M + ct * 4] = o;
            }
        }
    }
}

// ------- Aggregate, F=64, one feature-half (16 dwords = one 64B line) ------
// Lane: quarter = lane>>4 picks edge within group of 4; q = lane&15 owns
// feature dword qbase+q. 4 edges per vmem. Dead lanes: w=0, s=0 (harmless).
// out cols [2*(qbase+q), +1]; full epilogue (bias/self/relu) per half.
template <bool RELU>
__global__ __launch_bounds__(256) void agg64_half_kernel(const unsigned* __restrict__ xw32,
        const int2* __restrict__ csr, const int* __restrict__ row_start,
        const int* __restrict__ row_cnt, const float* __restrict__ dinv,
        const float* __restrict__ bias, float* __restrict__ out, int N, int qbase) {
    int wid = (int)((blockIdx.x * blockDim.x + threadIdx.x) >> 6);
    int lane = threadIdx.x & 63;
    if (wid >= N) return;
    const int quarter = lane >> 4;
    const int q = lane & 15;
    const unsigned long long* row =
        (const unsigned long long*)(csr + row_start[wid]);
    int cnt = row_cnt[wid];
    float a0l = 0.f, a0h = 0.f, a1l = 0.f, a1h = 0.f;
    for (int base = 0; base < cnt; base += 64) {
        int m = min(cnt - base, 64);
        int sx = 0, sy = 0;
        if (lane < m) {
            unsigned long long p = __builtin_nontemporal_load(row + base + lane);
            sx = (int)p; sy = (int)(p >> 32);
        }
        for (int j = 0; j < m; j += 8) {        // 8 edges: 2 vmem
            int   s0 = __shfl(sx, j + quarter);
            float w0 = __int_as_float(__shfl(sy, j + quarter));
            int   s1 = __shfl(sx, j + 4 + quarter);
            float w1 = __int_as_float(__shfl(sy, j + 4 + quarter));
            unsigned d0 = xw32[(size_t)s0 * 32 + qbase + q];
            unsigned d1 = xw32[(size_t)s1 * 32 + qbase + q];
            a0l = fmaf(w0, bflo(d0), a0l); a0h = fmaf(w0, bfhi(d0), a0h);
            a1l = fmaf(w1, bflo(d1), a1l); a1h = fmaf(w1, bfhi(d1), a1h);
        }
    }
    float al = a0l + a1l, ah = a0h + a1h;
    al += __shfl_xor(al, 16); ah += __shfl_xor(ah, 16);
    al += __shfl_xor(al, 32); ah += __shfl_xor(ah, 32);
    if (lane < 16) {
        float dd = dinv[wid];
        unsigned ds = xw32[(size_t)wid * 32 + qbase + q];  // self, prescaled
        int col = 2 * (qbase + q);
        float ol = dd * (al + bflo(ds)) + bias[col];
        float oh = dd * (ah + bfhi(ds)) + bias[col + 1];
        if (RELU) { ol = fmaxf(ol, 0.f); oh = fmaxf(oh, 0.f); }
        unsigned long long pk =
            ((unsigned long long)__float_as_uint(oh) << 32) | __float_as_uint(ol);
        __builtin_nontemporal_store(pk,
            (unsigned long long*)&out[(size_t)wid * 64 + col]);
    }
}

// ------- Aggregate, F=40 single pass: 2 edges/vmem (half = lane>>5) --------
__global__ __launch_bounds__(256) void agg40_kernel(const unsigned* __restrict__ xw32,
        const int2* __restrict__ csr, const int* __restrict__ row_start,
        const int* __restrict__ row_cnt, const float* __restrict__ dinv,
        const float* __restrict__ bias, float* __restrict__ out, int N) {
    constexpr int Q = 20;
    int wid = (int)((blockIdx.x * blockDim.x + threadIdx.x) >> 6);
    int lane = threadIdx.x & 63;
    if (wid >= N) return;
    const int half = lane >> 5;
    const int q = lane & 31;
    const bool qok = (q < Q);
    const unsigned long long* row =
        (const unsigned long long*)(csr + row_start[wid]);
    int cnt = row_cnt[wid];
    float a0l = 0.f, a0h = 0.f, a1l = 0.f, a1h = 0.f;
    for (int base = 0; base < cnt; base += 64) {
        int m = min(cnt - base, 64);
        int sx = 0, sy = 0;
        if (lane < m) {
            unsigned long long p = __builtin_nontemporal_load(row + base + lane);
            sx = (int)p; sy = (int)(p >> 32);
        }
        for (int j = 0; j < m; j += 4) {        // 4 edges: 2 vmem
            int   s0 = __shfl(sx, j + half);
            float w0 = __int_as_float(__shfl(sy, j + half));
            int   s1 = __shfl(sx, j + 2 + half);
            float w1 = __int_as_float(__shfl(sy, j + 2 + half));
            unsigned d0 = 0, d1 = 0;
            if (qok) {
                d0 = xw32[(size_t)s0 * Q + q];
                d1 = xw32[(size_t)s1 * Q + q];
            }
            a0l = fmaf(w0, bflo(d0), a0l); a0h = fmaf(w0, bfhi(d0), a0h);
            a1l = fmaf(w1, bflo(d1), a1l); a1h = fmaf(w1, bfhi(d1), a1h);
        }
    }
    float al = a0l + a1l, ah = a0h + a1h;
    al += __shfl_xor(al, 32);
    ah += __shfl_xor(ah, 32);
    if (half == 0 && qok) {
        float dd = dinv[wid];
        unsigned ds = xw32[(size_t)wid * Q + q];
        int col = 2 * q;
        float ol = dd * (al + bflo(ds)) + bias[col];
        float oh = dd * (ah + bfhi(ds)) + bias[col + 1];
        unsigned long long pk =
            ((unsigned long long)__float_as_uint(oh) << 32) | __float_as_uint(ol);
        __builtin_nontemporal_store(pk,
            (unsigned long long*)&out[(size_t)wid * 40 + col]);
    }
}

static inline size_t ws_align(size_t x) { return (x + 255) & ~(size_t)255; }

extern "C" void kernel_launch(void* const* d_in, const int* in_sizes, int n_in,
                              void* d_out, int out_size, void* d_ws, size_t ws_size,
                              hipStream_t stream) {
    const float* x  = (const float*)d_in[0];
    const int*   ei = (const int*)d_in[1];
    const float* ew = (const float*)d_in[2];
    const float* W1 = (const float*)d_in[3];
    const float* b1 = (const float*)d_in[4];
    const float* W2 = (const float*)d_in[5];
    const float* b2 = (const float*)d_in[6];
    const float* W3 = (const float*)d_in[7];
    const float* b3 = (const float*)d_in[8];
    float* out = (float*)d_out;

    const int N = in_sizes[0] / 128;   // 50000
    const int E = in_sizes[1] / 2;     // 1600000
    const int* src = ei;
    const int* dst = ei + E;
    const int nbins = (N + 255) >> 8;  // 196

    char* p = (char*)d_ws;
    size_t off = 0;
    auto alloc = [&](size_t bytes) -> char* {
        char* q = p + off;
        off = ws_align(off + bytes);
        return q;
    };
    int*   row_start  = (int*)  alloc((size_t)N * 4);
    int*   row_cnt    = (int*)  alloc((size_t)N * 4);
    float* dinv       = (float*)alloc((size_t)N * 4);
    int*   bin_cursor = (int*)  alloc((size_t)nbins * 4);
    unsigned short* xwbuf = (unsigned short*)alloc((size_t)N * 64 * 2);  // bf16 dinv*xW
    float* hbuf       = (float*)alloc((size_t)N * 64 * 4);               // fp32 h
    size_t remain = (ws_size > off) ? (ws_size - off) : 0;
    int bcap = (int)(remain / ((size_t)nbins * 8));
    if (bcap > BCAP_MAX) bcap = BCAP_MAX;
    int2* binned = (int2*)alloc((size_t)nbins * (size_t)bcap * 8);

    hipMemsetAsync(bin_cursor, 0, (size_t)nbins * 4, stream);

    const int tb = (E + TILE - 1) / TILE;   // 391 tiles
    const int gb = (N + 63) / 64;           // 782 GEMM tiles
    const int ab = (N + 3) / 4;             // one wave per node

    bin_scatter_kernel<<<tb, 1024, 0, stream>>>(src, dst, ew, bin_cursor, binned, E, bcap);
    bin_group_kernel<<<nbins, 1024, 0, stream>>>(binned, bin_cursor, row_start, row_cnt, dinv, N, bcap);

    const unsigned* xw32 = (const unsigned*)xwbuf;

    gemm_kernel<128, 64><<<gb, 256, 0, stream>>>(x, W1, dinv, xwbuf, N);
    agg64_half_kernel<true ><<<ab, 256, 0, stream>>>(xw32, binned, row_start, row_cnt, dinv, b1, hbuf, N, 0);
    agg64_half_kernel<true ><<<ab, 256, 0, stream>>>(xw32, binned, row_start, row_cnt, dinv, b1, hbuf, N, 16);
    gemm_kernel<64, 64><<<gb, 256, 0, stream>>>(hbuf, W2, dinv, xwbuf, N);
    agg64_half_kernel<true ><<<ab, 256, 0, stream>>>(xw32, binned, row_start, row_cnt, dinv, b2, hbuf, N, 0);
    agg64_half_kernel<true ><<<ab, 256, 0, stream>>>(xw32, binned, row_start, row_cnt, dinv, b2, hbuf, N, 16);
    gemm_kernel<64, 40><<<gb, 256, 0, stream>>>(hbuf, W3, dinv, xwbuf, N);
    agg40_kernel<<<ab, 256, 0, stream>>>(xw32, binned, row_start, row_cnt, dinv, b3, out, N);
}

// Round 10
// 286.976 us; speedup vs baseline: 1.1733x; 1.1733x over previous
//
#include <hip/hip_runtime.h>

// GCN 3-layer: out = GCNconv3(relu(GCNconv2(relu(GCNconv1(x)))))
//
// R10 = R6 (best: 288 us) + deterministic binning (no global atomics):
//   A1. bin_count: per-tile 256-bin LDS histogram -> cnt[bin][tile]
//   A2. bin_scan: block per bin scans tile counts -> exclusive base + total
//   A3. bin_scatter: LDS sort per 4096-edge tile, flush to precomputed base
//       (replaces 391 serialized device atomics per bin_cursor address ~24us)
//   B.  bin_group: per-bin 256-key LDS counting sort -> CSR + deg/dinv free.
//   C.  per layer: fp32 GEMM -> bf16 Y[s] = dinv[s]*(X@W)[s];
//       agg (R6 readlane form): out = dinv[d]*(sum_e ew*Y[s] + Y[d]) + b.
//
// Agg model (R5-R9 evidence): bound by line-fill concurrency
// (~2 lines/edge / (MSHR~32 / ~300cyc) = ~16.5 cyc/edge); bytes (R5),
// vmem count (R7), ws-residency splits (R8/R9) all neutral-or-worse; NT on
// edge list hurts (R3/R9). bf16 = min precision -> 2 lines/edge irreducible.

#define TILE 4096
#define BCAP_MAX 9216   // per-bin capacity; bin load ~Binom mean 8163 sd 90

static __device__ __forceinline__ float4 f4zero() { return make_float4(0.f, 0.f, 0.f, 0.f); }

static __device__ __forceinline__ unsigned short f2bf_rne(float x) {
    unsigned u = __float_as_uint(x);
    u += 0x7FFFu + ((u >> 16) & 1u);     // round-to-nearest-even
    return (unsigned short)(u >> 16);
}
static __device__ __forceinline__ float bf2f(unsigned short b) {
    return __uint_as_float((unsigned)b << 16);
}

// ---------------- A1: per-tile bin histogram -> cnt[bin][tile] -------------
__global__ __launch_bounds__(1024) void bin_count_kernel(
        const int* __restrict__ dst, int* __restrict__ cnt, int E, int ntiles) {
    __shared__ int h[256];
    const int tid = threadIdx.x;
    const int t = blockIdx.x;
    if (tid < 256) h[tid] = 0;
    __syncthreads();
    const int e0 = t * TILE;
    #pragma unroll
    for (int j = 0; j < 4; ++j) {
        int e = e0 + j * 1024 + tid;
        if (e < E) atomicAdd(&h[dst[e] >> 8], 1);
    }
    __syncthreads();
    if (tid < 256) cnt[tid * ntiles + t] = h[tid];
}

// ---------------- A2: per-bin exclusive scan over tiles --------------------
__global__ __launch_bounds__(512) void bin_scan_kernel(
        int* __restrict__ cnt, int* __restrict__ bintotal, int ntiles) {
    __shared__ int buf[512];
    const int b = blockIdx.x;
    const int tid = threadIdx.x;
    int v = (tid < ntiles) ? cnt[b * ntiles + tid] : 0;
    buf[tid] = v;
    __syncthreads();
    for (int off = 1; off < 512; off <<= 1) {   // inclusive Hillis-Steele
        int x = buf[tid];
        int a = (tid >= off) ? buf[tid - off] : 0;
        __syncthreads();
        buf[tid] = x + a;
        __syncthreads();
    }
    if (tid < ntiles) cnt[b * ntiles + tid] = buf[tid] - v;   // exclusive base
    if (tid == 0) bintotal[b] = buf[511];
}

// ---------------- A3: tile-level LDS binning, deterministic flush ----------
__global__ __launch_bounds__(1024) void bin_scatter_kernel(
        const int* __restrict__ src, const int* __restrict__ dst,
        const float* __restrict__ ew, const int* __restrict__ cntbase,
        int2* __restrict__ binned, int E, int bcap, int ntiles) {
    __shared__ int cnt[256];
    __shared__ int scan[256];
    __shared__ int gbase[256];
    __shared__ int2 sorted[TILE];
    __shared__ unsigned char binof[TILE];
    const int tid = threadIdx.x;
    const int t = blockIdx.x;
    const int e0 = t * TILE;

    if (tid < 256) cnt[tid] = 0;
    __syncthreads();

    int mypk[4]; float myew[4]; int mybin[4]; int myrank[4]; bool myok[4];
    #pragma unroll
    for (int j = 0; j < 4; ++j) {
        int e = e0 + j * 1024 + tid;
        myok[j] = (e < E);
        if (myok[j]) {
            int d = dst[e];
            int s = src[e];
            myew[j]   = ew[e];
            mybin[j]  = d >> 8;
            mypk[j]   = (s << 8) | (d & 255);     // src:24b | dst_local:8b
            myrank[j] = atomicAdd(&cnt[mybin[j]], 1);
        }
    }
    __syncthreads();
    if (tid < 256) scan[tid] = cnt[tid];
    __syncthreads();
    for (int off = 1; off < 256; off <<= 1) {     // inclusive Hillis-Steele
        int v = 0;
        if (tid < 256) { v = scan[tid]; if (tid >= off) v += scan[tid - off]; }
        __syncthreads();
        if (tid < 256) scan[tid] = v;
        __syncthreads();
    }
    if (tid < 256) gbase[tid] = cntbase[tid * ntiles + t];   // no atomics
    __syncthreads();
    #pragma unroll
    for (int j = 0; j < 4; ++j) {
        if (myok[j]) {
            int b = mybin[j];
            int slot = (scan[b] - cnt[b]) + myrank[j];   // excl prefix + rank
            sorted[slot] = make_int2(mypk[j], __float_as_int(myew[j]));
            binof[slot]  = (unsigned char)b;
        }
    }
    __syncthreads();
    const int total = scan[255];
    for (int i = tid; i < total; i += 1024) {
        int b = binof[i];
        int pos = gbase[b] + (i - (scan[b] - cnt[b]));
        if (pos < bcap)   // statistically unreachable; prevents OOB
            binned[(size_t)b * bcap + pos] = sorted[i];
    }
}

// ---------------- B: per-bin counting sort -> CSR (+ deg/dinv) -------------
__global__ __launch_bounds__(1024) void bin_group_kernel(
        int2* __restrict__ binned, const int* __restrict__ bintotal,
        int* __restrict__ row_start, int* __restrict__ row_cnt,
        float* __restrict__ dinv, int N, int bcap) {
    __shared__ int   cntl[256];
    __shared__ float degl[256];
    __shared__ int   scan[256];
    __shared__ int   run[256];
    __shared__ int2  sorted[BCAP_MAX];
    const int b = blockIdx.x;
    const int tid = threadIdx.x;
    int n = bintotal[b];
    if (n > bcap) n = bcap;
    if (tid < 256) { cntl[tid] = 0; degl[tid] = 0.f; }
    __syncthreads();

    int2* seg = binned + (size_t)b * bcap;
    for (int i = tid; i < n; i += 1024) {
        int2 v = seg[i];
        int dl = v.x & 255;
        atomicAdd(&cntl[dl], 1);
        atomicAdd(&degl[dl], __int_as_float(v.y));
    }
    __syncthreads();
    if (tid < 256) scan[tid] = cntl[tid];
    __syncthreads();
    for (int off = 1; off < 256; off <<= 1) {
        int v = 0;
        if (tid < 256) { v = scan[tid]; if (tid >= off) v += scan[tid - off]; }
        __syncthreads();
        if (tid < 256) scan[tid] = v;
        __syncthreads();
    }
    if (tid < 256) {
        int ex = scan[tid] - cntl[tid];
        int d = (b << 8) + tid;
        if (d < N) {
            row_start[d] = b * bcap + ex;
            row_cnt[d]   = cntl[tid];
            dinv[d]      = rsqrtf(degl[tid] + 1.0f);
        }
        run[tid] = ex;
    }
    __syncthreads();
    for (int i = tid; i < n; i += 1024) {
        int2 v = seg[i];
        int dl = v.x & 255;
        int r = atomicAdd(&run[dl], 1);
        sorted[r] = make_int2(v.x >> 8, v.y);    // {src, ew}
    }
    __syncthreads();
    for (int i = tid; i < n; i += 1024)          // in-place: reads done above
        seg[i] = sorted[i];
}

// --- GEMM: Y[N,M](bf16) = dinv[r] * (X[N,K](fp32) @ W[K,M](fp32)), RNE -----
template <int K, int M>
__global__ __launch_bounds__(256) void gemm_kernel(const float* __restrict__ X,
        const float* __restrict__ W, const float* __restrict__ dinv,
        unsigned short* __restrict__ Y, int N) {
    constexpr int KP = K + 4;
    __shared__ float xs[64 * KP];
    __shared__ float ws[K * M];
    const int tid = threadIdx.x;
    const int row0 = blockIdx.x * 64;

    for (int i = tid * 4; i < K * M; i += 1024)
        *(float4*)&ws[i] = *(const float4*)&W[i];

    const int nrows = min(64, N - row0);
    for (int i = tid * 4; i < 64 * K; i += 1024) {
        int r = i / K, k = i % K;
        float4 v = f4zero();
        if (r < nrows) v = *(const float4*)&X[(size_t)(row0 + r) * K + k];
        *(float4*)&xs[r * KP + k] = v;
    }
    __syncthreads();

    const int ct = tid & 15, rt = tid >> 4;
    const bool cok = (ct * 4 < M);
    float acc[4][4] = {};
    for (int k = 0; k < K; ++k) {
        float a0 = xs[(rt +  0) * KP + k];
        float a1 = xs[(rt + 16) * KP + k];
        float a2 = xs[(rt + 32) * KP + k];
        float a3 = xs[(rt + 48) * KP + k];
        float4 bv = cok ? *(const float4*)&ws[k * M + ct * 4] : f4zero();
        acc[0][0] += a0 * bv.x; acc[0][1] += a0 * bv.y; acc[0][2] += a0 * bv.z; acc[0][3] += a0 * bv.w;
        acc[1][0] += a1 * bv.x; acc[1][1] += a1 * bv.y; acc[1][2] += a1 * bv.z; acc[1][3] += a1 * bv.w;
        acc[2][0] += a2 * bv.x; acc[2][1] += a2 * bv.y; acc[2][2] += a2 * bv.z; acc[2][3] += a2 * bv.w;
        acc[3][0] += a3 * bv.x; acc[3][1] += a3 * bv.y; acc[3][2] += a3 * bv.z; acc[3][3] += a3 * bv.w;
    }
    if (cok) {
        #pragma unroll
        for (int i = 0; i < 4; ++i) {
            int r = row0 + rt + 16 * i;
            if (r < N) {
                float dd = dinv[r];
                ushort4 o;
                o.x = f2bf_rne(acc[i][0] * dd); o.y = f2bf_rne(acc[i][1] * dd);
                o.z = f2bf_rne(acc[i][2] * dd); o.w = f2bf_rne(acc[i][3] * dd);
                *(ushort4*)&Y[(size_t)r * M + ct * 4] = o;
            }
        }
    }
}

// ---------------- Aggregate (R6-proven): one wave per node -----------------
// xw bf16 dinv-prescaled. 1 vmem/edge (row gather); {src,w} via readlane.
// out = dinv[d]*(sum_e ew*xw[s] + xw[d]) + b.
template <int F, bool RELU>
__global__ __launch_bounds__(256) void agg_kernel(const unsigned short* __restrict__ xw,
        const int2* __restrict__ csr, const int* __restrict__ row_start,
        const int* __restrict__ row_cnt, const float* __restrict__ dinv,
        const float* __restrict__ bias, float* __restrict__ out, int N) {
    int wid = (int)((blockIdx.x * blockDim.x + threadIdx.x) >> 6);
    int lane = threadIdx.x & 63;
    if (wid >= N) return;
    const int2* row = csr + row_start[wid];
    int cnt = row_cnt[wid];
    float acc0 = 0.f, acc1 = 0.f;
    for (int base = 0; base < cnt; base += 64) {
        int m = min(cnt - base, 64);
        int2 ed = make_int2(0, 0);
        if (lane < m) ed = row[base + lane];
        int j = 0;
        for (; j + 8 <= m; j += 8) {
            #pragma unroll
            for (int u = 0; u < 8; u += 2) {
                int s0 = __builtin_amdgcn_readlane(ed.x, j + u);
                int w0 = __builtin_amdgcn_readlane(ed.y, j + u);
                int s1 = __builtin_amdgcn_readlane(ed.x, j + u + 1);
                int w1 = __builtin_amdgcn_readlane(ed.y, j + u + 1);
                acc0 = fmaf(__int_as_float(w0), bf2f(xw[(size_t)s0 * F + lane]), acc0);
                acc1 = fmaf(__int_as_float(w1), bf2f(xw[(size_t)s1 * F + lane]), acc1);
            }
        }
        for (; j < m; ++j) {
            int s = __builtin_amdgcn_readlane(ed.x, j);
            int w = __builtin_amdgcn_readlane(ed.y, j);
            acc0 = fmaf(__int_as_float(w), bf2f(xw[(size_t)s * F + lane]), acc0);
        }
    }
    if (lane < F) {
        float dd = dinv[wid];
        float selfv = bf2f(xw[(size_t)wid * F + lane]);   // already dinv-scaled
        float acc = dd * (acc0 + acc1 + selfv) + bias[lane];
        if (RELU) acc = fmaxf(acc, 0.f);
        out[(size_t)wid * F + lane] = acc;
    }
}

static inline size_t ws_align(size_t x) { return (x + 255) & ~(size_t)255; }

extern "C" void kernel_launch(void* const* d_in, const int* in_sizes, int n_in,
                              void* d_out, int out_size, void* d_ws, size_t ws_size,
                              hipStream_t stream) {
    const float* x  = (const float*)d_in[0];
    const int*   ei = (const int*)d_in[1];
    const float* ew = (const float*)d_in[2];
    const float* W1 = (const float*)d_in[3];
    const float* b1 = (const float*)d_in[4];
    const float* W2 = (const float*)d_in[5];
    const float* b2 = (const float*)d_in[6];
    const float* W3 = (const float*)d_in[7];
    const float* b3 = (const float*)d_in[8];
    float* out = (float*)d_out;

    const int N = in_sizes[0] / 128;   // 50000
    const int E = in_sizes[1] / 2;     // 1600000
    const int* src = ei;
    const int* dst = ei + E;
    const int nbins = (N + 255) >> 8;         // 196
    const int ntiles = (E + TILE - 1) / TILE; // 391 (must be <= 512 for scan)

    char* p = (char*)d_ws;
    size_t off = 0;
    auto alloc = [&](size_t bytes) -> char* {
        char* q = p + off;
        off = ws_align(off + bytes);
        return q;
    };
    int*   row_start = (int*)  alloc((size_t)N * 4);
    int*   row_cnt   = (int*)  alloc((size_t)N * 4);
    float* dinv      = (float*)alloc((size_t)N * 4);
    int*   cntbase   = (int*)  alloc((size_t)256 * ntiles * 4);  // [bin][tile]
    int*   bintotal  = (int*)  alloc((size_t)256 * 4);
    unsigned short* xwbuf = (unsigned short*)alloc((size_t)N * 64 * 2);  // bf16 dinv*xW
    float* hbuf      = (float*)alloc((size_t)N * 64 * 4);                // fp32 h
    size_t remain = (ws_size > off) ? (ws_size - off) : 0;
    int bcap = (int)(remain / ((size_t)nbins * 8));
    if (bcap > BCAP_MAX) bcap = BCAP_MAX;
    int2* binned = (int2*)alloc((size_t)nbins * (size_t)bcap * 8);

    const int gb = (N + 63) / 64;           // 782 GEMM tiles
    const int ab = (N + 3) / 4;             // one wave per node

    bin_count_kernel<<<ntiles, 1024, 0, stream>>>(dst, cntbase, E, ntiles);
    bin_scan_kernel<<<256, 512, 0, stream>>>(cntbase, bintotal, ntiles);
    bin_scatter_kernel<<<ntiles, 1024, 0, stream>>>(src, dst, ew, cntbase, binned, E, bcap, ntiles);
    bin_group_kernel<<<nbins, 1024, 0, stream>>>(binned, bintotal, row_start, row_cnt, dinv, N, bcap);

    gemm_kernel<128, 64><<<gb, 256, 0, stream>>>(x, W1, dinv, xwbuf, N);
    agg_kernel<64, true><<<ab, 256, 0, stream>>>(xwbuf, binned, row_start, row_cnt, dinv, b1, hbuf, N);
    gemm_kernel<64, 64><<<gb, 256, 0, stream>>>(hbuf, W2, dinv, xwbuf, N);
    agg_kernel<64, true><<<ab, 256, 0, stream>>>(xwbuf, binned, row_start, row_cnt, dinv, b2, hbuf, N);
    gemm_kernel<64, 40><<<gb, 256, 0, stream>>>(hbuf, W3, dinv, xwbuf, N);
    agg_kernel<40, false><<<ab, 256, 0, stream>>>(xwbuf, binned, row_start, row_cnt, dinv, b3, out, N);
}